// Round 5
// baseline (206.872 us; speedup 1.0000x reference)
//
#include <hip/hip_runtime.h>

#define FDIM 64

// ---- bf16 helpers (manual, RNE) ----
__device__ __forceinline__ unsigned f2bf(float f) {
    unsigned u = __float_as_uint(f);
    u += 0x7fffu + ((u >> 16) & 1u);
    return u >> 16;
}
__device__ __forceinline__ float bflo(unsigned u) { return __uint_as_float(u << 16); }
__device__ __forceinline__ float bfhi(unsigned u) { return __uint_as_float(u & 0xffff0000u); }

// ============== CSR build: hierarchical counting sort by dst ==============

__global__ __launch_bounds__(256) void k_hist(const int* __restrict__ ei,
                                              int* __restrict__ hist, int nE) {
    __shared__ int lh[256];
    int t = threadIdx.x;
    lh[t] = 0;
    __syncthreads();
    int base = blockIdx.x * 8192;
    #pragma unroll 4
    for (int i = 0; i < 32; ++i) {
        int e = base + i * 256 + t;
        if (e < nE) atomicAdd(&lh[ei[nE + e] >> 8], 1);
    }
    __syncthreads();
    if (lh[t]) atomicAdd(&hist[t], lh[t]);
}

__global__ void k_scan256(const int* __restrict__ hist, int* __restrict__ bbase,
                          int* __restrict__ cursor, int nE) {
    __shared__ int s[256];
    int t = threadIdx.x;
    int v = hist[t];
    s[t] = v;
    __syncthreads();
    #pragma unroll
    for (int off = 1; off < 256; off <<= 1) {
        int u = (t >= off) ? s[t - off] : 0;
        __syncthreads();
        s[t] += u;
        __syncthreads();
    }
    bbase[t]  = s[t] - v;
    cursor[t] = s[t] - v;
    if (t == 255) bbase[256] = nE;
}

__global__ __launch_bounds__(256) void k_coarse(const int* __restrict__ ei,
                                                int* __restrict__ cursor,
                                                int* __restrict__ packed, int nE) {
    __shared__ int lh[256], gb[256], lc[256];
    int t = threadIdx.x;
    lh[t] = 0; lc[t] = 0;
    __syncthreads();
    int base = blockIdx.x * 8192;
    int bins[32], vals[32];
    #pragma unroll 4
    for (int i = 0; i < 32; ++i) {
        int e = base + i * 256 + t;
        if (e < nE) {
            int s = ei[e];
            int d = ei[nE + e];
            bins[i] = d >> 8;
            vals[i] = (s << 8) | (d & 255);
            atomicAdd(&lh[bins[i]], 1);
        } else {
            bins[i] = -1;
        }
    }
    __syncthreads();
    gb[t] = atomicAdd(&cursor[t], lh[t]);
    __syncthreads();
    #pragma unroll 4
    for (int i = 0; i < 32; ++i) {
        int b = bins[i];
        if (b >= 0) {
            int p = gb[b] + atomicAdd(&lc[b], 1);
            packed[p] = vals[i];
        }
    }
}

// Stage 4: per coarse bucket -> exact CSR + per-row src-ASCENDING order.
// Rank-based sort: O(c^2) independent LDS reads, NO serial dependent chain
// (the R4 insertion sort was latency-bound at 1 wave/SIMD).

__global__ __launch_bounds__(256) void k_fine(const int* __restrict__ packed,
                                              const int* __restrict__ bbase,
                                              float* __restrict__ dis,
                                              int* __restrict__ rowStart,
                                              unsigned short* __restrict__ sortedSrc,
                                              int nE, int n) {
    __shared__ int cnt[256], loc[256], lc[256];
    __shared__ unsigned short srcArr[6144];
    int t = threadIdx.x;
    int b = blockIdx.x;
    int lo = bbase[b], hi = bbase[b + 1];
    int sz = hi - lo;
    cnt[t] = 0; lc[t] = 0;
    __syncthreads();
    for (int k = lo + t; k < hi; k += 256)
        atomicAdd(&cnt[packed[k] & 255], 1);
    __syncthreads();

    int c = cnt[t];
    int node = (b << 8) + t;
    dis[node] = rsqrtf((float)c + 1.0f);

    loc[t] = c;
    __syncthreads();
    #pragma unroll
    for (int off = 1; off < 256; off <<= 1) {
        int u = (t >= off) ? loc[t - off] : 0;
        __syncthreads();
        loc[t] += u;
        __syncthreads();
    }
    int excl = loc[t] - c;
    rowStart[node] = lo + excl;
    if (b == 0 && t == 0) rowStart[n] = nE;
    __syncthreads();
    loc[t] = excl;
    __syncthreads();

    if (sz <= 6144) {
        for (int k = lo + t; k < hi; k += 256) {
            int v = packed[k];
            int dl = v & 255;
            int p = loc[dl] + atomicAdd(&lc[dl], 1);
            srcArr[p] = (unsigned short)(v >> 8);
        }
        __syncthreads();
        // rank-sort own row: rank_j = #{i : key_i < key_j || (==, i<j)}.
        // Independent LDS reads -> pipelined, not latency-serialized.
        int s0 = excl;
        for (int j = 0; j < c; ++j) {
            unsigned short kj = srcArr[s0 + j];
            int r = 0;
            for (int i = 0; i < c; ++i) {
                unsigned short ki = srcArr[s0 + i];
                r += (ki < kj) || (ki == kj && i < j);
            }
            sortedSrc[lo + s0 + r] = kj;
        }
    } else {
        // fallback (statistically unreachable): unsorted, still correct
        for (int k = lo + t; k < hi; k += 256) {
            int v = packed[k];
            int dl = v & 255;
            int p = loc[dl] + atomicAdd(&lc[dl], 1);
            sortedSrc[lo + p] = (unsigned short)(v >> 8);
        }
    }
}

// ======== GEMM: HSb = bf16( (X @ W) * dis[row] ) ========

__global__ __launch_bounds__(256) void k_gemm64s(const float* __restrict__ X,
                                                 const float* __restrict__ W,
                                                 const float* __restrict__ dis,
                                                 unsigned* __restrict__ Hb) {
    __shared__ float Ws[64 * 64];     // [k][f]
    __shared__ float XsT[64 * 68];    // [k][r]

    const int tid  = threadIdx.x;
    const int row0 = blockIdx.x * 64;

    for (int i = tid; i < 4096; i += 256) Ws[i] = W[i];
    for (int i = tid; i < 4096; i += 256) {
        int r = i >> 6, k = i & 63;
        XsT[k * 68 + r] = X[(row0 + r) * FDIM + k];
    }
    __syncthreads();

    const int tx = tid & 15;   // feature quad
    const int ty = tid >> 4;   // row quad

    float4 acc0 = {0,0,0,0}, acc1 = {0,0,0,0}, acc2 = {0,0,0,0}, acc3 = {0,0,0,0};

    #pragma unroll
    for (int k = 0; k < 64; ++k) {
        float4 wv = *(const float4*)&Ws[k * 64 + tx * 4];
        float4 xv = *(const float4*)&XsT[k * 68 + ty * 4];
        acc0.x = fmaf(xv.x, wv.x, acc0.x); acc0.y = fmaf(xv.x, wv.y, acc0.y);
        acc0.z = fmaf(xv.x, wv.z, acc0.z); acc0.w = fmaf(xv.x, wv.w, acc0.w);
        acc1.x = fmaf(xv.y, wv.x, acc1.x); acc1.y = fmaf(xv.y, wv.y, acc1.y);
        acc1.z = fmaf(xv.y, wv.z, acc1.z); acc1.w = fmaf(xv.y, wv.w, acc1.w);
        acc2.x = fmaf(xv.z, wv.x, acc2.x); acc2.y = fmaf(xv.z, wv.y, acc2.y);
        acc2.z = fmaf(xv.z, wv.z, acc2.z); acc2.w = fmaf(xv.z, wv.w, acc2.w);
        acc3.x = fmaf(xv.w, wv.x, acc3.x); acc3.y = fmaf(xv.w, wv.y, acc3.y);
        acc3.z = fmaf(xv.w, wv.z, acc3.z); acc3.w = fmaf(xv.w, wv.w, acc3.w);
    }

    float d0 = dis[row0 + ty * 4 + 0];
    float d1 = dis[row0 + ty * 4 + 1];
    float d2 = dis[row0 + ty * 4 + 2];
    float d3 = dis[row0 + ty * 4 + 3];

    uint2* H2 = (uint2*)Hb;   // row stride = 64 bf16 = 16 uint2
    uint2 o;
    o.x = f2bf(acc0.x * d0) | (f2bf(acc0.y * d0) << 16);
    o.y = f2bf(acc0.z * d0) | (f2bf(acc0.w * d0) << 16);
    H2[(row0 + ty * 4 + 0) * 16 + tx] = o;
    o.x = f2bf(acc1.x * d1) | (f2bf(acc1.y * d1) << 16);
    o.y = f2bf(acc1.z * d1) | (f2bf(acc1.w * d1) << 16);
    H2[(row0 + ty * 4 + 1) * 16 + tx] = o;
    o.x = f2bf(acc2.x * d2) | (f2bf(acc2.y * d2) << 16);
    o.y = f2bf(acc2.z * d2) | (f2bf(acc2.w * d2) << 16);
    H2[(row0 + ty * 4 + 2) * 16 + tx] = o;
    o.x = f2bf(acc3.x * d3) | (f2bf(acc3.y * d3) << 16);
    o.y = f2bf(acc3.z * d3) | (f2bf(acc3.w * d3) << 16);
    H2[(row0 + ty * 4 + 3) * 16 + tx] = o;
}

// ===== aggregation: out = relu(dis[d]*(sum_{s in N(d)} HSb[s] + HSb[d]) + b) =====

__global__ __launch_bounds__(256) void k_agg(const unsigned* __restrict__ Hb,
                                             const float* __restrict__ dis,
                                             const int* __restrict__ rowStart,
                                             const unsigned short* __restrict__ esrc,
                                             const float* __restrict__ bias,
                                             float* __restrict__ out) {
    const int lane = threadIdx.x & 63;
    const int row  = blockIdx.x * 4 + (threadIdx.x >> 6);
    const int fq   = lane & 7;    // uint4 chunk within row (8 bf16)
    const int eq   = lane >> 3;   // 0..7 edge streams

    const int start = rowStart[row];
    const int end   = rowStart[row + 1];

    const uint4* H = (const uint4*)Hb;   // row stride = 8 uint4 (128 B)

    float4 a0 = {0,0,0,0}, a1 = {0,0,0,0};

    for (int k = start + eq; k < end; k += 8) {
        int s = (int)esrc[k];
        uint4 v = H[s * 8 + fq];
        a0.x += bflo(v.x); a0.y += bfhi(v.x);
        a0.z += bflo(v.y); a0.w += bfhi(v.y);
        a1.x += bflo(v.z); a1.y += bfhi(v.z);
        a1.z += bflo(v.w); a1.w += bfhi(v.w);
    }

    #pragma unroll
    for (int m = 8; m <= 32; m <<= 1) {
        a0.x += __shfl_xor(a0.x, m, 64); a0.y += __shfl_xor(a0.y, m, 64);
        a0.z += __shfl_xor(a0.z, m, 64); a0.w += __shfl_xor(a0.w, m, 64);
        a1.x += __shfl_xor(a1.x, m, 64); a1.y += __shfl_xor(a1.y, m, 64);
        a1.z += __shfl_xor(a1.z, m, 64); a1.w += __shfl_xor(a1.w, m, 64);
    }

    if (eq == 0) {
        uint4 sv = H[row * 8 + fq];
        float ds = dis[row];
        float4 b0 = ((const float4*)bias)[fq * 2];
        float4 b1 = ((const float4*)bias)[fq * 2 + 1];
        float4 r0, r1;
        r0.x = fmaxf(fmaf(a0.x + bflo(sv.x), ds, b0.x), 0.f);
        r0.y = fmaxf(fmaf(a0.y + bfhi(sv.x), ds, b0.y), 0.f);
        r0.z = fmaxf(fmaf(a0.z + bflo(sv.y), ds, b0.z), 0.f);
        r0.w = fmaxf(fmaf(a0.w + bfhi(sv.y), ds, b0.w), 0.f);
        r1.x = fmaxf(fmaf(a1.x + bflo(sv.z), ds, b1.x), 0.f);
        r1.y = fmaxf(fmaf(a1.y + bfhi(sv.z), ds, b1.y), 0.f);
        r1.z = fmaxf(fmaf(a1.z + bflo(sv.w), ds, b1.z), 0.f);
        r1.w = fmaxf(fmaf(a1.w + bfhi(sv.w), ds, b1.w), 0.f);
        float4* O = (float4*)out;        // row stride = 16 float4
        O[row * 16 + fq * 2]     = r0;
        O[row * 16 + fq * 2 + 1] = r1;
    }
}

// ================= launch =================

extern "C" void kernel_launch(void* const* d_in, const int* in_sizes, int n_in,
                              void* d_out, int out_size, void* d_ws, size_t ws_size,
                              hipStream_t stream) {
    const float* x  = (const float*)d_in[0];
    const int*   ei = (const int*)d_in[1];
    const float* W1 = (const float*)d_in[2];
    const float* b1 = (const float*)d_in[3];
    const float* W2 = (const float*)d_in[4];
    const float* b2 = (const float*)d_in[5];

    const int N = in_sizes[0] / FDIM;    // 65536
    const int E = in_sizes[1] / 2;       // 1048576

    char* ws = (char*)d_ws;
    float*          dis       = (float*)(ws);                 // 256 KB
    int*            rowStart  = (int*)  (ws + 262144);        // (N+1)*4
    int*            hist      = (int*)  (ws + 524544);
    int*            bbase     = (int*)  (ws + 525568);
    int*            cursor    = (int*)  (ws + 526848);
    unsigned short* sortedSrc = (unsigned short*)(ws + 528384);   // E*2 = 2 MB
    // packed (4 MB) overlays HSb (8 MB): packed dead before gemm writes HSb.
    int*            packed    = (int*)  (ws + 528384 + 2097152);
    unsigned*       HSb       = (unsigned*)(ws + 528384 + 2097152);  // N*64 bf16 = 8 MB
    float*          B         = (float*)d_out;

    const int histBlocks = (E + 8191) / 8192;   // 128

    // ---- CSR build + degrees (shared by both layers) ----
    hipMemsetAsync(hist, 0, 256 * sizeof(int), stream);
    k_hist   <<<histBlocks, 256, 0, stream>>>(ei, hist, E);
    k_scan256<<<1, 256, 0, stream>>>(hist, bbase, cursor, E);
    k_coarse <<<histBlocks, 256, 0, stream>>>(ei, cursor, packed, E);
    k_fine   <<<256, 256, 0, stream>>>(packed, bbase, dis, rowStart, sortedSrc, E, N);

    // ---- layer 1 ----
    k_gemm64s<<<N / 64, 256, 0, stream>>>(x, W1, dis, HSb);
    k_agg    <<<N / 4, 256, 0, stream>>>(HSb, dis, rowStart, sortedSrc, b1, B);

    // ---- layer 2 ----
    k_gemm64s<<<N / 64, 256, 0, stream>>>(B, W2, dis, HSb);
    k_agg    <<<N / 4, 256, 0, stream>>>(HSb, dis, rowStart, sortedSrc, b2, (float*)d_out);
}

// Round 6
// 154.937 us; speedup vs baseline: 1.3352x; 1.3352x over previous
//
#include <hip/hip_runtime.h>

#define FDIM 64

// ---- bf16 helpers (manual, RNE) ----
__device__ __forceinline__ unsigned f2bf(float f) {
    unsigned u = __float_as_uint(f);
    u += 0x7fffu + ((u >> 16) & 1u);
    return u >> 16;
}
__device__ __forceinline__ float bflo(unsigned u) { return __uint_as_float(u << 16); }
__device__ __forceinline__ float bfhi(unsigned u) { return __uint_as_float(u & 0xffff0000u); }

// ============== CSR build: hierarchical counting sort by dst ==============

__global__ __launch_bounds__(256) void k_hist(const int* __restrict__ ei,
                                              int* __restrict__ hist, int nE) {
    __shared__ int lh[256];
    int t = threadIdx.x;
    lh[t] = 0;
    __syncthreads();
    int base = blockIdx.x * 8192;
    #pragma unroll 4
    for (int i = 0; i < 32; ++i) {
        int e = base + i * 256 + t;
        if (e < nE) atomicAdd(&lh[ei[nE + e] >> 8], 1);
    }
    __syncthreads();
    if (lh[t]) atomicAdd(&hist[t], lh[t]);
}

__global__ void k_scan256(const int* __restrict__ hist, int* __restrict__ bbase,
                          int* __restrict__ cursor, int nE) {
    __shared__ int s[256];
    int t = threadIdx.x;
    int v = hist[t];
    s[t] = v;
    __syncthreads();
    #pragma unroll
    for (int off = 1; off < 256; off <<= 1) {
        int u = (t >= off) ? s[t - off] : 0;
        __syncthreads();
        s[t] += u;
        __syncthreads();
    }
    bbase[t]  = s[t] - v;
    cursor[t] = s[t] - v;
    if (t == 255) bbase[256] = nE;
}

__global__ __launch_bounds__(256) void k_coarse(const int* __restrict__ ei,
                                                int* __restrict__ cursor,
                                                int* __restrict__ packed, int nE) {
    __shared__ int lh[256], gb[256], lc[256];
    int t = threadIdx.x;
    lh[t] = 0; lc[t] = 0;
    __syncthreads();
    int base = blockIdx.x * 8192;
    int bins[32], vals[32];
    #pragma unroll 4
    for (int i = 0; i < 32; ++i) {
        int e = base + i * 256 + t;
        if (e < nE) {
            int s = ei[e];
            int d = ei[nE + e];
            bins[i] = d >> 8;
            vals[i] = (s << 8) | (d & 255);
            atomicAdd(&lh[bins[i]], 1);
        } else {
            bins[i] = -1;
        }
    }
    __syncthreads();
    gb[t] = atomicAdd(&cursor[t], lh[t]);
    __syncthreads();
    #pragma unroll 4
    for (int i = 0; i < 32; ++i) {
        int b = bins[i];
        if (b >= 0) {
            int p = gb[b] + atomicAdd(&lc[b], 1);
            packed[p] = vals[i];
        }
    }
}

// Stage 4: per coarse bucket -> exact CSR + degrees. UNSORTED within row
// (R4/R5 ablation: in-row sort cost 55-63 us at 1 block/CU, can't pay).

__global__ __launch_bounds__(256) void k_fine(const int* __restrict__ packed,
                                              const int* __restrict__ bbase,
                                              float* __restrict__ dis,
                                              int* __restrict__ rowStart,
                                              unsigned short* __restrict__ sortedSrc,
                                              int nE, int n) {
    __shared__ int cnt[256], loc[256], lc[256];
    int t = threadIdx.x;
    int b = blockIdx.x;
    int lo = bbase[b], hi = bbase[b + 1];
    cnt[t] = 0; lc[t] = 0;
    __syncthreads();
    for (int k = lo + t; k < hi; k += 256)
        atomicAdd(&cnt[packed[k] & 255], 1);
    __syncthreads();

    int c = cnt[t];
    int node = (b << 8) + t;
    dis[node] = rsqrtf((float)c + 1.0f);

    loc[t] = c;
    __syncthreads();
    #pragma unroll
    for (int off = 1; off < 256; off <<= 1) {
        int u = (t >= off) ? loc[t - off] : 0;
        __syncthreads();
        loc[t] += u;
        __syncthreads();
    }
    int excl = loc[t] - c;
    rowStart[node] = lo + excl;
    if (b == 0 && t == 0) rowStart[n] = nE;
    __syncthreads();
    loc[t] = excl;
    __syncthreads();

    for (int k = lo + t; k < hi; k += 256) {
        int v = packed[k];
        int dl = v & 255;
        int p = loc[dl] + atomicAdd(&lc[dl], 1);
        sortedSrc[lo + p] = (unsigned short)(v >> 8);
    }
}

// ======== GEMM: HSb = bf16( (X @ W) * dis[row] ) ========

__global__ __launch_bounds__(256) void k_gemm64s(const float* __restrict__ X,
                                                 const float* __restrict__ W,
                                                 const float* __restrict__ dis,
                                                 unsigned* __restrict__ Hb) {
    __shared__ float Ws[64 * 64];     // [k][f]
    __shared__ float XsT[64 * 68];    // [k][r]

    const int tid  = threadIdx.x;
    const int row0 = blockIdx.x * 64;

    for (int i = tid; i < 4096; i += 256) Ws[i] = W[i];
    for (int i = tid; i < 4096; i += 256) {
        int r = i >> 6, k = i & 63;
        XsT[k * 68 + r] = X[(row0 + r) * FDIM + k];
    }
    __syncthreads();

    const int tx = tid & 15;   // feature quad
    const int ty = tid >> 4;   // row quad

    float4 acc0 = {0,0,0,0}, acc1 = {0,0,0,0}, acc2 = {0,0,0,0}, acc3 = {0,0,0,0};

    #pragma unroll
    for (int k = 0; k < 64; ++k) {
        float4 wv = *(const float4*)&Ws[k * 64 + tx * 4];
        float4 xv = *(const float4*)&XsT[k * 68 + ty * 4];
        acc0.x = fmaf(xv.x, wv.x, acc0.x); acc0.y = fmaf(xv.x, wv.y, acc0.y);
        acc0.z = fmaf(xv.x, wv.z, acc0.z); acc0.w = fmaf(xv.x, wv.w, acc0.w);
        acc1.x = fmaf(xv.y, wv.x, acc1.x); acc1.y = fmaf(xv.y, wv.y, acc1.y);
        acc1.z = fmaf(xv.y, wv.z, acc1.z); acc1.w = fmaf(xv.y, wv.w, acc1.w);
        acc2.x = fmaf(xv.z, wv.x, acc2.x); acc2.y = fmaf(xv.z, wv.y, acc2.y);
        acc2.z = fmaf(xv.z, wv.z, acc2.z); acc2.w = fmaf(xv.z, wv.w, acc2.w);
        acc3.x = fmaf(xv.w, wv.x, acc3.x); acc3.y = fmaf(xv.w, wv.y, acc3.y);
        acc3.z = fmaf(xv.w, wv.z, acc3.z); acc3.w = fmaf(xv.w, wv.w, acc3.w);
    }

    float d0 = dis[row0 + ty * 4 + 0];
    float d1 = dis[row0 + ty * 4 + 1];
    float d2 = dis[row0 + ty * 4 + 2];
    float d3 = dis[row0 + ty * 4 + 3];

    uint2* H2 = (uint2*)Hb;   // row stride = 64 bf16 = 16 uint2
    uint2 o;
    o.x = f2bf(acc0.x * d0) | (f2bf(acc0.y * d0) << 16);
    o.y = f2bf(acc0.z * d0) | (f2bf(acc0.w * d0) << 16);
    H2[(row0 + ty * 4 + 0) * 16 + tx] = o;
    o.x = f2bf(acc1.x * d1) | (f2bf(acc1.y * d1) << 16);
    o.y = f2bf(acc1.z * d1) | (f2bf(acc1.w * d1) << 16);
    H2[(row0 + ty * 4 + 1) * 16 + tx] = o;
    o.x = f2bf(acc2.x * d2) | (f2bf(acc2.y * d2) << 16);
    o.y = f2bf(acc2.z * d2) | (f2bf(acc2.w * d2) << 16);
    H2[(row0 + ty * 4 + 2) * 16 + tx] = o;
    o.x = f2bf(acc3.x * d3) | (f2bf(acc3.y * d3) << 16);
    o.y = f2bf(acc3.z * d3) | (f2bf(acc3.w * d3) << 16);
    H2[(row0 + ty * 4 + 3) * 16 + tx] = o;
}

// ===== aggregation: out = relu(dis[d]*(sum_{s in N(d)} HSb[s] + HSb[d]) + b) =====

__global__ __launch_bounds__(256) void k_agg(const unsigned* __restrict__ Hb,
                                             const float* __restrict__ dis,
                                             const int* __restrict__ rowStart,
                                             const unsigned short* __restrict__ esrc,
                                             const float* __restrict__ bias,
                                             float* __restrict__ out) {
    const int lane = threadIdx.x & 63;
    const int row  = blockIdx.x * 4 + (threadIdx.x >> 6);
    const int fq   = lane & 7;    // uint4 chunk within row (8 bf16)
    const int eq   = lane >> 3;   // 0..7 edge streams

    const int start = rowStart[row];
    const int end   = rowStart[row + 1];

    const uint4* H = (const uint4*)Hb;   // row stride = 8 uint4 (128 B)

    float4 a0 = {0,0,0,0}, a1 = {0,0,0,0};

    for (int k = start + eq; k < end; k += 8) {
        int s = (int)esrc[k];
        uint4 v = H[s * 8 + fq];
        a0.x += bflo(v.x); a0.y += bfhi(v.x);
        a0.z += bflo(v.y); a0.w += bfhi(v.y);
        a1.x += bflo(v.z); a1.y += bfhi(v.z);
        a1.z += bflo(v.w); a1.w += bfhi(v.w);
    }

    #pragma unroll
    for (int m = 8; m <= 32; m <<= 1) {
        a0.x += __shfl_xor(a0.x, m, 64); a0.y += __shfl_xor(a0.y, m, 64);
        a0.z += __shfl_xor(a0.z, m, 64); a0.w += __shfl_xor(a0.w, m, 64);
        a1.x += __shfl_xor(a1.x, m, 64); a1.y += __shfl_xor(a1.y, m, 64);
        a1.z += __shfl_xor(a1.z, m, 64); a1.w += __shfl_xor(a1.w, m, 64);
    }

    if (eq == 0) {
        uint4 sv = H[row * 8 + fq];
        float ds = dis[row];
        float4 b0 = ((const float4*)bias)[fq * 2];
        float4 b1 = ((const float4*)bias)[fq * 2 + 1];
        float4 r0, r1;
        r0.x = fmaxf(fmaf(a0.x + bflo(sv.x), ds, b0.x), 0.f);
        r0.y = fmaxf(fmaf(a0.y + bfhi(sv.x), ds, b0.y), 0.f);
        r0.z = fmaxf(fmaf(a0.z + bflo(sv.y), ds, b0.z), 0.f);
        r0.w = fmaxf(fmaf(a0.w + bfhi(sv.y), ds, b0.w), 0.f);
        r1.x = fmaxf(fmaf(a1.x + bflo(sv.z), ds, b1.x), 0.f);
        r1.y = fmaxf(fmaf(a1.y + bfhi(sv.z), ds, b1.y), 0.f);
        r1.z = fmaxf(fmaf(a1.z + bflo(sv.w), ds, b1.z), 0.f);
        r1.w = fmaxf(fmaf(a1.w + bfhi(sv.w), ds, b1.w), 0.f);
        float4* O = (float4*)out;        // row stride = 16 float4
        O[row * 16 + fq * 2]     = r0;
        O[row * 16 + fq * 2 + 1] = r1;
    }
}

// ================= launch =================

extern "C" void kernel_launch(void* const* d_in, const int* in_sizes, int n_in,
                              void* d_out, int out_size, void* d_ws, size_t ws_size,
                              hipStream_t stream) {
    const float* x  = (const float*)d_in[0];
    const int*   ei = (const int*)d_in[1];
    const float* W1 = (const float*)d_in[2];
    const float* b1 = (const float*)d_in[3];
    const float* W2 = (const float*)d_in[4];
    const float* b2 = (const float*)d_in[5];

    const int N = in_sizes[0] / FDIM;    // 65536
    const int E = in_sizes[1] / 2;       // 1048576

    char* ws = (char*)d_ws;
    float*          dis       = (float*)(ws);                 // 256 KB
    int*            rowStart  = (int*)  (ws + 262144);        // (N+1)*4
    int*            hist      = (int*)  (ws + 524544);
    int*            bbase     = (int*)  (ws + 525568);
    int*            cursor    = (int*)  (ws + 526848);
    unsigned short* sortedSrc = (unsigned short*)(ws + 528384);   // E*2 = 2 MB
    // packed (4 MB) overlays HSb (8 MB): packed dead before gemm writes HSb.
    int*            packed    = (int*)  (ws + 528384 + 2097152);
    unsigned*       HSb       = (unsigned*)(ws + 528384 + 2097152);  // N*64 bf16 = 8 MB
    float*          B         = (float*)d_out;

    const int histBlocks = (E + 8191) / 8192;   // 128

    // ---- CSR build + degrees (shared by both layers) ----
    hipMemsetAsync(hist, 0, 256 * sizeof(int), stream);
    k_hist   <<<histBlocks, 256, 0, stream>>>(ei, hist, E);
    k_scan256<<<1, 256, 0, stream>>>(hist, bbase, cursor, E);
    k_coarse <<<histBlocks, 256, 0, stream>>>(ei, cursor, packed, E);
    k_fine   <<<256, 256, 0, stream>>>(packed, bbase, dis, rowStart, sortedSrc, E, N);

    // ---- layer 1 ----
    k_gemm64s<<<N / 64, 256, 0, stream>>>(x, W1, dis, HSb);
    k_agg    <<<N / 4, 256, 0, stream>>>(HSb, dis, rowStart, sortedSrc, b1, B);

    // ---- layer 2 ----
    k_gemm64s<<<N / 64, 256, 0, stream>>>(B, W2, dis, HSb);
    k_agg    <<<N / 4, 256, 0, stream>>>(HSb, dis, rowStart, sortedSrc, b2, (float*)d_out);
}